// Round 12
// baseline (75.589 us; speedup 1.0000x reference)
//
#include <hip/hip_runtime.h>

// B=131072 points (D=16 fp32), K=256 centers. Out (fp32): [B] argmin idx ++ [B,16] offsets.
//
// Round-12: PPL=4 over the ORIGINAL 16KB center layout.
// Evidence: r1 counters (VALUBusy 34%, stalls ~31us, occupancy-invariant) +
// monotone fit of r2/r5/r7/r8/r11 vs SMEM traffic -> bottleneck = scalar-cache
// (SMEM) bandwidth, a per-CU serialized resource. Fix: amortize each
// s_load_dwordx16 center row over 4 points/lane (halves SMEM bytes/point vs
// r5) while keeping the K$ working set at 16KB raw `centers` rows (r8's 34KB
// duplicated-pair table thrashed K$ - that was the confound, not PPL=4).
// VALU splat of scalar c into (v2f){c,c} is cheap relative to the fetch wall.
//
// Block = 256 thr = 4 waves, 256 points (lane l owns base+{0,64,128,192});
// wave w scans centers [64w,64w+64); k wave-uniform -> s_load broadcast.
// score = c2[k] - 2*x.c via acc={c2,c2} then d-ascending pk_fma — identical
// per-point arithmetic to r5/r11 (absmax 0). Strict < + ascending k/chunk =>
// lowest-k ties, matching jnp.argmin. Epilogue: r11's LDS center gather.

constexpr int Bn = 131072;
constexpr int Kn = 256;
constexpr int Dn = 16;
constexpr int PTS = 256;      // points per block (4 per lane)
constexpr int NW = 4;         // waves per block == K chunks
constexpr int KC = Kn / NW;   // 64 centers per wave

typedef float v2f __attribute__((ext_vector_type(2)));

__global__ __launch_bounds__(256, 2) void kmeans_kernel(
    const float* __restrict__ traj, const float* __restrict__ centers,
    float* __restrict__ out) {
  __shared__ float c2s[Kn];
  __shared__ float4 cs4[Kn][4];     // centers copy for the epilogue gather (16KB)
  __shared__ float sbest[NW * PTS];
  __shared__ int sbi[NW * PTS];
  __shared__ int swin[PTS];

  const int t = threadIdx.x;
  const int blk = blockIdx.x;

  // ---- Stage 1: thread t loads center row t, computes c2, stages row in LDS.
  {
    const float4* cp = reinterpret_cast<const float4*>(centers + t * Dn);
    float4 a = cp[0], b = cp[1], c = cp[2], d = cp[3];
    float s = 0.0f;
    s = fmaf(a.x, a.x, s); s = fmaf(a.y, a.y, s);
    s = fmaf(a.z, a.z, s); s = fmaf(a.w, a.w, s);
    s = fmaf(b.x, b.x, s); s = fmaf(b.y, b.y, s);
    s = fmaf(b.z, b.z, s); s = fmaf(b.w, b.w, s);
    s = fmaf(c.x, c.x, s); s = fmaf(c.y, c.y, s);
    s = fmaf(c.z, c.z, s); s = fmaf(c.w, c.w, s);
    s = fmaf(d.x, d.x, s); s = fmaf(d.y, d.y, s);
    s = fmaf(d.z, d.z, s); s = fmaf(d.w, d.w, s);
    c2s[t] = s;
    cs4[t][0] = a; cs4[t][1] = b; cs4[t][2] = c; cs4[t][3] = d;
  }
  __syncthreads();

  const int w = __builtin_amdgcn_readfirstlane(t >> 6);  // wave id (SGPR)
  const int l = t & 63;                                  // lane
  const int pbase = blk * PTS + l;     // lane's points: pbase + {0,64,128,192}

  // ---- Load y = -2*x for 4 points: ya[d]={p0,p1}, yb[d]={p2,p3}.
  v2f ya[Dn], yb[Dn];
  {
    const float4* x0 = reinterpret_cast<const float4*>(traj + (size_t)(pbase      ) * Dn);
    const float4* x1 = reinterpret_cast<const float4*>(traj + (size_t)(pbase +  64) * Dn);
    const float4* x2 = reinterpret_cast<const float4*>(traj + (size_t)(pbase + 128) * Dn);
    const float4* x3 = reinterpret_cast<const float4*>(traj + (size_t)(pbase + 192) * Dn);
#pragma unroll
    for (int q = 0; q < 4; ++q) {
      float4 a = x0[q], b = x1[q], c = x2[q], d = x3[q];
      ya[q * 4 + 0] = (v2f){-2.0f * a.x, -2.0f * b.x};
      ya[q * 4 + 1] = (v2f){-2.0f * a.y, -2.0f * b.y};
      ya[q * 4 + 2] = (v2f){-2.0f * a.z, -2.0f * b.z};
      ya[q * 4 + 3] = (v2f){-2.0f * a.w, -2.0f * b.w};
      yb[q * 4 + 0] = (v2f){-2.0f * c.x, -2.0f * d.x};
      yb[q * 4 + 1] = (v2f){-2.0f * c.y, -2.0f * d.y};
      yb[q * 4 + 2] = (v2f){-2.0f * c.z, -2.0f * d.z};
      yb[q * 4 + 3] = (v2f){-2.0f * c.w, -2.0f * d.w};
    }
  }

  float best0 = __builtin_inff(), best1 = __builtin_inff();
  float best2 = __builtin_inff(), best3 = __builtin_inff();
  int bi0 = 0, bi1 = 0, bi2 = 0, bi3 = 0;
  const int k0 = w * KC;
#pragma unroll 4
  for (int kk = 0; kk < KC; ++kk) {
    const int k = k0 + kk;
    const float* cr = centers + k * Dn;  // wave-uniform -> s_load_dwordx16
    const float c2k = c2s[k];
    v2f aa = (v2f){c2k, c2k};
    v2f ab = aa;
#pragma unroll
    for (int d = 0; d < Dn; ++d) {
      const float c = cr[d];             // SGPR; splat into both halves
      aa = ya[d] * (v2f){c, c} + aa;     // v_pk_fma_f32
      ab = yb[d] * (v2f){c, c} + ab;
    }
    if (aa.x < best0) { best0 = aa.x; bi0 = k; }  // strict <: lowest-k ties
    if (aa.y < best1) { best1 = aa.y; bi1 = k; }
    if (ab.x < best2) { best2 = ab.x; bi2 = k; }
    if (ab.y < best3) { best3 = ab.y; bi3 = k; }
  }
  sbest[w * PTS + l      ] = best0;  sbi[w * PTS + l      ] = bi0;
  sbest[w * PTS + l +  64] = best1;  sbi[w * PTS + l +  64] = bi1;
  sbest[w * PTS + l + 128] = best2;  sbi[w * PTS + l + 128] = bi2;
  sbest[w * PTS + l + 192] = best3;  sbi[w * PTS + l + 192] = bi3;
  __syncthreads();

  // ---- Cross-wave reduction: 256 threads, one per point. Ascending chunk
  // order + strict < keeps the lowest-k winner on exact ties.
  {
    float b0 = sbest[t];
    int i0 = sbi[t];
#pragma unroll
    for (int ww = 1; ww < NW; ++ww) {
      float b1 = sbest[ww * PTS + t];
      int i1 = sbi[ww * PTS + t];
      if (b1 < b0) { b0 = b1; i0 = i1; }
    }
    swin[t] = i0;
    out[blk * PTS + t] = (float)i0;  // idx output (fp32 buffer), coalesced
  }
  __syncthreads();

  // ---- Coalesced offset stores: 256 pts x 4 quarters = 1024 float4 ops.
  // x from traj (coalesced, L1-hot); center quarter from the LDS copy.
#pragma unroll
  for (int it = 0; it < 4; ++it) {
    const int id = it * 256 + t;
    const int pb = id >> 2, q = id & 3;
    const int pt = blk * PTS + pb;
    const int win = swin[pb];
    float4 xv = reinterpret_cast<const float4*>(traj + (size_t)pt * Dn)[q];
    float4 cv = cs4[win][q];                                  // LDS gather
    float4 o = make_float4(xv.x - cv.x, xv.y - cv.y, xv.z - cv.z, xv.w - cv.w);
    reinterpret_cast<float4*>(out + Bn)[(size_t)pt * 4 + q] = o;
  }
}

extern "C" void kernel_launch(void* const* d_in, const int* in_sizes, int n_in,
                              void* d_out, int out_size, void* d_ws, size_t ws_size,
                              hipStream_t stream) {
  (void)in_sizes; (void)n_in; (void)out_size; (void)d_ws; (void)ws_size;
  const float* traj = (const float*)d_in[0];     // [131072, 16]
  const float* centers = (const float*)d_in[1];  // [256, 16]
  float* out = (float*)d_out;                    // [131072] idx ++ [131072*16] offsets
  kmeans_kernel<<<Bn / PTS, 256, 0, stream>>>(traj, centers, out);
}